// Round 4
// baseline (3328.888 us; speedup 1.0000x reference)
//
#include <hip/hip_runtime.h>

// Causal self-attention block: x[B,T,C] -> qkv GEMM (bf16 MFMA) ->
// flash attention (fp32, causal, online softmax) -> proj GEMM (bf16 MFMA).
// B=4, T=2048, C=1024, H=16, D=64.

typedef unsigned short u16;
typedef unsigned int   u32;
typedef short bf16x8 __attribute__((ext_vector_type(8)));   // 8 bf16 in 4 VGPRs (guide §3)
typedef float f32x4  __attribute__((ext_vector_type(4)));

constexpr int BB = 4;
constexpr int TT = 2048;
constexpr int CC = 1024;
constexpr int HH = 16;
constexpr int DD = 64;

__device__ __forceinline__ u16 f2bf(float f) {
    u32 x = __float_as_uint(f);
    x += 0x7FFFu + ((x >> 16) & 1u);   // round-to-nearest-even
    return (u16)(x >> 16);
}

// ---------------------------------------------------------------------------
// Flat fp32 -> bf16 cast (x -> Xb). n4 = element count / 4.
// ---------------------------------------------------------------------------
__global__ __launch_bounds__(256)
void cast_bf16(const float* __restrict__ in, u16* __restrict__ out, int n4) {
    int i = blockIdx.x * blockDim.x + threadIdx.x;
    const int stride = gridDim.x * blockDim.x;
    for (; i < n4; i += stride) {
        float4 v = reinterpret_cast<const float4*>(in)[i];
        ushort4 o;
        o.x = f2bf(v.x); o.y = f2bf(v.y); o.z = f2bf(v.z); o.w = f2bf(v.w);
        reinterpret_cast<ushort4*>(out)[i] = o;
    }
}

// ---------------------------------------------------------------------------
// Transpose + cast: in fp32 [K][N] -> out bf16 [N][K]. K,N multiples of 32.
// ---------------------------------------------------------------------------
__global__ __launch_bounds__(256)
void transpose_cast(const float* __restrict__ in, u16* __restrict__ out,
                    int K, int N) {
    __shared__ u16 tile[32][33];
    const int n0 = blockIdx.x * 32, k0 = blockIdx.y * 32;
    const int tx = threadIdx.x & 31, ty = threadIdx.x >> 5;   // 32 x 8
    #pragma unroll
    for (int r = 0; r < 32; r += 8)
        tile[tx][ty + r] = f2bf(in[(size_t)(k0 + ty + r) * N + n0 + tx]);
    __syncthreads();
    #pragma unroll
    for (int r = 0; r < 32; r += 8)
        out[(size_t)(n0 + ty + r) * K + k0 + tx] = tile[ty + r][tx];
}

// ---------------------------------------------------------------------------
// bf16 MFMA GEMM: C[M,N] = A[M,K] @ Bt[N,K]^T + bias, fp32 accumulate.
// m97 structure: 128x128 tile, BK=32, 256 thr = 4 waves (2x2), each wave a
// 64x64 sub-tile = 4x4 mfma_f32_16x16x32_bf16 fragments.
// Staging via global_load_lds width-16 (linear LDS, wave-uniform dest):
//   lane l writes LDS base + l*16B == row-major [row=l>>2][16B-chunk=l&3]
//   (identity: l*16 == (l>>2)*64 + (l&3)*16 for a 32-k * 2B = 64B row).
// A-frag: lane l -> row (l&15), k = 8*(l>>4)+[0..7]  (contiguous b128 read)
// B-frag: lane l -> col (l&15), k = 8*(l>>4)+[0..7]  (same, from Bt)
// C/D:    col = lane&15, row = (lane>>4)*4 + reg     [m89-verified]
// MODE 0: Cout[M][N] = acc + bias.  MODE 1: QKV scatter to Qb/Kb/Vb [B*H][T][D].
// ---------------------------------------------------------------------------
template<int MODE>
__global__ __launch_bounds__(256)
void gemm_bf16(const u16* __restrict__ A, const u16* __restrict__ Bt,
               const float* __restrict__ bias, float* __restrict__ Cout,
               float* __restrict__ Qb, float* __restrict__ Kb,
               float* __restrict__ Vb, int M, int N, int K)
{
    constexpr int BM = 128, BN = 128, BK = 32;
    __shared__ __align__(16) u16 ldsA[BM * BK];   // [128 rows][32 k] = 8 KB
    __shared__ __align__(16) u16 ldsB[BN * BK];

    const int tid  = threadIdx.x;
    const int wave = tid >> 6, lane = tid & 63;
    const int wm = wave >> 1, wn = wave & 1;
    const int n0 = blockIdx.x * BN, m0 = blockIdx.y * BM;

    // staging: wave w stages rows [w*32, w*32+32) of A and of Bt,
    // two 1KB issues each (16 rows x 64B).
    const int srow = lane >> 2, skq = lane & 3;
    const char* gA = (const char*)(A  + (size_t)(m0 + wave * 32 + srow) * K) + skq * 16;
    const char* gB = (const char*)(Bt + (size_t)(n0 + wave * 32 + srow) * K) + skq * 16;
    char* lA = (char*)ldsA + wave * 2048;
    char* lB = (char*)ldsB + wave * 2048;
    const size_t rowskip = (size_t)16 * K * 2;   // 16 rows ahead, in bytes

    f32x4 acc[4][4];
    #pragma unroll
    for (int i = 0; i < 4; ++i)
        #pragma unroll
        for (int j = 0; j < 4; ++j) acc[i][j] = (f32x4){0.f, 0.f, 0.f, 0.f};

    const int fr = lane & 15, kq = lane >> 4;
    const char* rdA = (const char*)ldsA + (wm * 64 + fr) * 64 + kq * 16;
    const char* rdB = (const char*)ldsB + (wn * 64 + fr) * 64 + kq * 16;

    for (int k0 = 0; k0 < K; k0 += BK) {
        const char* ga = gA + (size_t)k0 * 2;
        const char* gb = gB + (size_t)k0 * 2;
        __builtin_amdgcn_global_load_lds((const __attribute__((address_space(1))) void*)ga,
                                         (__attribute__((address_space(3))) void*)lA, 16, 0, 0);
        __builtin_amdgcn_global_load_lds((const __attribute__((address_space(1))) void*)(ga + rowskip),
                                         (__attribute__((address_space(3))) void*)(lA + 1024), 16, 0, 0);
        __builtin_amdgcn_global_load_lds((const __attribute__((address_space(1))) void*)gb,
                                         (__attribute__((address_space(3))) void*)lB, 16, 0, 0);
        __builtin_amdgcn_global_load_lds((const __attribute__((address_space(1))) void*)(gb + rowskip),
                                         (__attribute__((address_space(3))) void*)(lB + 1024), 16, 0, 0);
        __syncthreads();   // compiler drains vmcnt before s_barrier

        bf16x8 af[4], bfv[4];
        #pragma unroll
        for (int f = 0; f < 4; ++f) af[f]  = *(const bf16x8*)(rdA + f * 1024);
        #pragma unroll
        for (int f = 0; f < 4; ++f) bfv[f] = *(const bf16x8*)(rdB + f * 1024);
        #pragma unroll
        for (int i = 0; i < 4; ++i)
            #pragma unroll
            for (int j = 0; j < 4; ++j)
                acc[i][j] = __builtin_amdgcn_mfma_f32_16x16x32_bf16(af[i], bfv[j], acc[i][j], 0, 0, 0);
        __syncthreads();
    }

    // epilogue
    #pragma unroll
    for (int i = 0; i < 4; ++i) {
        const int mbase = m0 + wm * 64 + i * 16 + (lane >> 4) * 4;
        #pragma unroll
        for (int j = 0; j < 4; ++j) {
            const int n = n0 + wn * 64 + j * 16 + (lane & 15);
            const float bv = bias[n];
            #pragma unroll
            for (int r = 0; r < 4; ++r) {
                const int m = mbase + r;
                const float val = acc[i][j][r] + bv;
                if (MODE == 0) {
                    Cout[(size_t)m * N + n] = val;
                } else {
                    const int which = n >> 10;        // 0=q 1=k 2=v
                    const int rr = n & 1023;
                    const int h = rr >> 6, d = rr & 63;
                    const int bb = m >> 11, t = m & 2047;
                    float* dst = (which == 0 ? Qb : which == 1 ? Kb : Vb);
                    dst[((size_t)(bb * HH + h) * TT + t) * DD + d] = val;
                }
            }
        }
    }
}

// ---------------------------------------------------------------------------
// Flash attention, fp32, causal, exact softmax (deferred-max rescale).
// 8 lanes per q-row (each owns 8 of D=64); wave = 8 rows; block = 32 rows.
// K/V rows stream from L1/L2 (512 KB per bh). Output stored bf16 -> Yb.
// ---------------------------------------------------------------------------
__global__ __launch_bounds__(256)
void flash_attn_f32(const float* __restrict__ Q, const float* __restrict__ K,
                    const float* __restrict__ V, u16* __restrict__ Y)
{
    const int bh   = blockIdx.y;        // 0..63
    const int b    = bh >> 4;
    const int h    = bh & 15;
    const int tid  = threadIdx.x;
    const int wave = tid >> 6;
    const int lane = tid & 63;
    const int grp  = lane >> 3;         // row within wave
    const int sub  = lane & 7;          // d-slice
    const int row  = blockIdx.x * 32 + wave * 8 + grp;
    const int d0   = sub * 8;

    const float* Qrow  = Q + ((size_t)bh * TT + row) * DD + d0;
    const float* Kbase = K + (size_t)bh * TT * DD + d0;
    const float* Vbase = V + (size_t)bh * TT * DD + d0;

    float q8[8];
    *(float4*)&q8[0] = *(const float4*)(Qrow);
    *(float4*)&q8[4] = *(const float4*)(Qrow + 4);

    float o8[8] = {0.f, 0.f, 0.f, 0.f, 0.f, 0.f, 0.f, 0.f};
    float mval = -1e30f;
    float lsum = 0.f;

    const int jend = blockIdx.x * 32 + wave * 8 + 8;   // last row of wave + 1

    #pragma unroll 2
    for (int j = 0; j < jend; ++j) {
        const float* Krow = Kbase + (size_t)j * DD;
        float k8[8];
        *(float4*)&k8[0] = *(const float4*)(Krow);
        *(float4*)&k8[4] = *(const float4*)(Krow + 4);
        float part = 0.f;
        #pragma unroll
        for (int i = 0; i < 8; ++i) part = fmaf(q8[i], k8[i], part);
        part += __shfl_xor(part, 1);
        part += __shfl_xor(part, 2);
        part += __shfl_xor(part, 4);
        float s = part * 0.125f;                 // 1/sqrt(64)
        if (j > row) s = -1e30f;                 // causal mask
        if (__any(s > mval + 8.f)) {             // deferred-max rescale (rare)
            const float mnew = fmaxf(mval, s);
            const float c = __expf(mval - mnew);
            lsum *= c;
            #pragma unroll
            for (int i = 0; i < 8; ++i) o8[i] *= c;
            mval = mnew;
        }
        const float p = __expf(s - mval);        // bounded by e^8
        lsum += p;
        const float* Vrow = Vbase + (size_t)j * DD;
        float v8[8];
        *(float4*)&v8[0] = *(const float4*)(Vrow);
        *(float4*)&v8[4] = *(const float4*)(Vrow + 4);
        #pragma unroll
        for (int i = 0; i < 8; ++i) o8[i] = fmaf(p, v8[i], o8[i]);
    }

    const float inv_l = 1.f / lsum;
    u16* Yp = Y + ((size_t)(b * TT + row)) * CC + h * DD + d0;
    ushort4 lo, hi;
    lo.x = f2bf(o8[0] * inv_l); lo.y = f2bf(o8[1] * inv_l);
    lo.z = f2bf(o8[2] * inv_l); lo.w = f2bf(o8[3] * inv_l);
    hi.x = f2bf(o8[4] * inv_l); hi.y = f2bf(o8[5] * inv_l);
    hi.z = f2bf(o8[6] * inv_l); hi.w = f2bf(o8[7] * inv_l);
    *(ushort4*)(Yp)     = lo;
    *(ushort4*)(Yp + 4) = hi;
}

// ---------------------------------------------------------------------------
extern "C" void kernel_launch(void* const* d_in, const int* in_sizes, int n_in,
                              void* d_out, int out_size, void* d_ws, size_t ws_size,
                              hipStream_t stream)
{
    const float* x      = (const float*)d_in[0];
    const float* W_attn = (const float*)d_in[1];
    const float* b_attn = (const float*)d_in[2];
    const float* W_proj = (const float*)d_in[3];
    const float* b_proj = (const float*)d_in[4];
    float* out = (float*)d_out;

    // workspace layout (125.8 MB total; Xb and Yb alias — Xb is dead after
    // GEMM1, Yb is written afterwards, stream-ordered):
    char* w = (char*)d_ws;
    float* Qb = (float*)w;  w += (size_t)BB * HH * TT * DD * 4;   // 33.55 MB
    float* Kb = (float*)w;  w += (size_t)BB * HH * TT * DD * 4;
    float* Vb = (float*)w;  w += (size_t)BB * HH * TT * DD * 4;
    u16*  Xb  = (u16*)w;    w += (size_t)BB * TT * CC * 2;        // 16.78 MB (also Yb)
    u16*  WaT = (u16*)w;    w += (size_t)CC * 3 * CC * 2;         //  6.29 MB
    u16*  WpT = (u16*)w;    w += (size_t)CC * CC * 2;             //  2.10 MB
    u16*  Yb  = Xb;

    const dim3 blk(256);

    // 0) casts / transposes (bf16 operand prep)
    cast_bf16<<<2048, blk, 0, stream>>>(x, Xb, BB * TT * CC / 4);
    transpose_cast<<<dim3(3 * CC / 32, CC / 32), blk, 0, stream>>>(W_attn, WaT, CC, 3 * CC);
    transpose_cast<<<dim3(CC / 32, CC / 32), blk, 0, stream>>>(W_proj, WpT, CC, CC);

    // 1) qkv GEMM -> scatter Q/K/V [B*H][T][D] fp32
    gemm_bf16<1><<<dim3(3 * CC / 128, BB * TT / 128), blk, 0, stream>>>(
        Xb, WaT, b_attn, nullptr, Qb, Kb, Vb, BB * TT, 3 * CC, CC);

    // 2) flash attention -> Yb bf16 [B,T,C]  (overwrites Xb, now dead)
    flash_attn_f32<<<dim3(TT / 32, BB * HH), blk, 0, stream>>>(Qb, Kb, Vb, Yb);

    // 3) out = Yb @ W_proj + b_proj (fp32 out)
    gemm_bf16<0><<<dim3(CC / 128, BB * TT / 128), blk, 0, stream>>>(
        Yb, WpT, b_proj, out, nullptr, nullptr, nullptr, BB * TT, CC, CC);
}

// Round 7
// 458.567 us; speedup vs baseline: 7.2593x; 7.2593x over previous
//
#include <hip/hip_runtime.h>

// Causal self-attention: x -> qkv GEMM (bf16 MFMA, scatters bf16 Q/K/V) ->
// MFMA flash attention (bf16 operands, fp32 softmax/accum) -> proj GEMM.
// B=4, T=2048, C=1024, H=16, D=64.

typedef unsigned short u16;
typedef unsigned int   u32;
typedef short bf16x8 __attribute__((ext_vector_type(8)));
typedef float f32x4  __attribute__((ext_vector_type(4)));
typedef u16   u16x8  __attribute__((ext_vector_type(8)));

constexpr int BB = 4;
constexpr int TT = 2048;
constexpr int CC = 1024;
constexpr int HH = 16;
constexpr int DD = 64;

__device__ __forceinline__ u16 f2bf(float f) {
    u32 x = __float_as_uint(f);
    x += 0x7FFFu + ((x >> 16) & 1u);
    return (u16)(x >> 16);
}

// ---------------------------------------------------------------------------
__global__ __launch_bounds__(256)
void cast_bf16(const float* __restrict__ in, u16* __restrict__ out, int n4) {
    int i = blockIdx.x * blockDim.x + threadIdx.x;
    const int stride = gridDim.x * blockDim.x;
    for (; i < n4; i += stride) {
        float4 v = reinterpret_cast<const float4*>(in)[i];
        ushort4 o;
        o.x = f2bf(v.x); o.y = f2bf(v.y); o.z = f2bf(v.z); o.w = f2bf(v.w);
        reinterpret_cast<ushort4*>(out)[i] = o;
    }
}

__global__ __launch_bounds__(256)
void transpose_cast(const float* __restrict__ in, u16* __restrict__ out,
                    int K, int N) {
    __shared__ u16 tile[32][33];
    const int n0 = blockIdx.x * 32, k0 = blockIdx.y * 32;
    const int tx = threadIdx.x & 31, ty = threadIdx.x >> 5;
    #pragma unroll
    for (int r = 0; r < 32; r += 8)
        tile[tx][ty + r] = f2bf(in[(size_t)(k0 + ty + r) * N + n0 + tx]);
    __syncthreads();
    #pragma unroll
    for (int r = 0; r < 32; r += 8)
        out[(size_t)(n0 + ty + r) * K + k0 + tx] = tile[ty + r][tx];
}

// ---------------------------------------------------------------------------
// bf16 MFMA GEMM (m97 structure, 128x128, BK=32).  MODE 0: fp32 C out.
// MODE 1: scatter bf16 into Qw/Kw/Vw [B*H][T][D]; Q scaled by 1/8 (1/sqrt(D)).
// ---------------------------------------------------------------------------
template<int MODE>
__global__ __launch_bounds__(256)
void gemm_bf16(const u16* __restrict__ A, const u16* __restrict__ Bt,
               const float* __restrict__ bias, float* __restrict__ Cout,
               u16* __restrict__ Qw, u16* __restrict__ Kw,
               u16* __restrict__ Vw, int M, int N, int K)
{
    constexpr int BM = 128, BN = 128, BK = 32;
    __shared__ __align__(16) u16 ldsA[BM * BK];
    __shared__ __align__(16) u16 ldsB[BN * BK];

    const int tid  = threadIdx.x;
    const int wave = tid >> 6, lane = tid & 63;
    const int wm = wave >> 1, wn = wave & 1;
    const int n0 = blockIdx.x * BN, m0 = blockIdx.y * BM;

    const int srow = lane >> 2, skq = lane & 3;
    const char* gA = (const char*)(A  + (size_t)(m0 + wave * 32 + srow) * K) + skq * 16;
    const char* gB = (const char*)(Bt + (size_t)(n0 + wave * 32 + srow) * K) + skq * 16;
    char* lA = (char*)ldsA + wave * 2048;
    char* lB = (char*)ldsB + wave * 2048;
    const size_t rowskip = (size_t)16 * K * 2;

    f32x4 acc[4][4];
    #pragma unroll
    for (int i = 0; i < 4; ++i)
        #pragma unroll
        for (int j = 0; j < 4; ++j) acc[i][j] = (f32x4){0.f, 0.f, 0.f, 0.f};

    const int fr = lane & 15, kq = lane >> 4;
    const char* rdA = (const char*)ldsA + (wm * 64 + fr) * 64 + kq * 16;
    const char* rdB = (const char*)ldsB + (wn * 64 + fr) * 64 + kq * 16;

    for (int k0 = 0; k0 < K; k0 += BK) {
        const char* ga = gA + (size_t)k0 * 2;
        const char* gb = gB + (size_t)k0 * 2;
        __builtin_amdgcn_global_load_lds((const __attribute__((address_space(1))) void*)ga,
                                         (__attribute__((address_space(3))) void*)lA, 16, 0, 0);
        __builtin_amdgcn_global_load_lds((const __attribute__((address_space(1))) void*)(ga + rowskip),
                                         (__attribute__((address_space(3))) void*)(lA + 1024), 16, 0, 0);
        __builtin_amdgcn_global_load_lds((const __attribute__((address_space(1))) void*)gb,
                                         (__attribute__((address_space(3))) void*)lB, 16, 0, 0);
        __builtin_amdgcn_global_load_lds((const __attribute__((address_space(1))) void*)(gb + rowskip),
                                         (__attribute__((address_space(3))) void*)(lB + 1024), 16, 0, 0);
        __syncthreads();

        bf16x8 af[4], bfv[4];
        #pragma unroll
        for (int f = 0; f < 4; ++f) af[f]  = *(const bf16x8*)(rdA + f * 1024);
        #pragma unroll
        for (int f = 0; f < 4; ++f) bfv[f] = *(const bf16x8*)(rdB + f * 1024);
        #pragma unroll
        for (int i = 0; i < 4; ++i)
            #pragma unroll
            for (int j = 0; j < 4; ++j)
                acc[i][j] = __builtin_amdgcn_mfma_f32_16x16x32_bf16(af[i], bfv[j], acc[i][j], 0, 0, 0);
        __syncthreads();
    }

    #pragma unroll
    for (int i = 0; i < 4; ++i) {
        const int mbase = m0 + wm * 64 + i * 16 + (lane >> 4) * 4;
        #pragma unroll
        for (int j = 0; j < 4; ++j) {
            const int n = n0 + wn * 64 + j * 16 + (lane & 15);
            const float bv = bias[n];
            #pragma unroll
            for (int r = 0; r < 4; ++r) {
                const int m = mbase + r;
                const float val = acc[i][j][r] + bv;
                if (MODE == 0) {
                    Cout[(size_t)m * N + n] = val;
                } else {
                    const int which = n >> 10;        // 0=q 1=k 2=v
                    const int rr = n & 1023;
                    const int hh = rr >> 6, dd = rr & 63;
                    const int bb = m >> 11, tt = m & 2047;
                    u16* dst = (which == 0 ? Qw : which == 1 ? Kw : Vw);
                    const float v2 = (which == 0) ? val * 0.125f : val;
                    dst[((size_t)(bb * HH + hh) * TT + tt) * DD + dd] = f2bf(v2);
                }
            }
        }
    }
}

// ---------------------------------------------------------------------------
// MFMA flash attention (causal). Q,K,V bf16 [B*H][T][D], Y bf16 [B][T][C].
// Block: 4 waves, 64 q-rows (wave w -> rows q0+16w..+15). KV tiles of 64.
// QK^T: A=Q (hoisted regs), B=K (LDS, swizzled via pre-swizzled g->lds src).
// Softmax fp32, online, exact (Q pre-scaled by 1/8 in GEMM1).
// P: D-layout -> LDS (per-wave 2KB, XOR swizzle) -> A-frag reads.
// PV: B=V^T (LDS [d][key], swizzle ^(((d>>3)^(d&7))&7)<<4, conflict-free).
// ---------------------------------------------------------------------------
__global__ __launch_bounds__(256)
void mfma_attn(const u16* __restrict__ Q, const u16* __restrict__ K,
               const u16* __restrict__ V, u16* __restrict__ Y)
{
    const int bh = blockIdx.y, b = bh >> 4, h = bh & 15;
    const int qb = blockIdx.x, q0 = qb * 64;
    const int tid = threadIdx.x, w = tid >> 6, l = tid & 63;
    const int g = l >> 4, c = l & 15;

    __shared__ __align__(16) u16 ldsK[64 * 64];    // [key][d], swizzled
    __shared__ __align__(16) u16 ldsVT[64 * 64];   // [d][key], swizzled
    __shared__ __align__(16) u16 ldsP[4][16 * 64]; // per-wave [q][key], swizzled

    const u16* Qg = Q + (size_t)bh * TT * DD;
    const u16* Kg = K + (size_t)bh * TT * DD;
    const u16* Vg = V + (size_t)bh * TT * DD;

    // Q A-frags hoisted: row(m) = c -> global q0+16w+c; k(d) = 32*hh + 8g + i
    bf16x8 qf[2];
    {
        const u16* qp = Qg + (size_t)(q0 + w * 16 + c) * DD + g * 8;
        qf[0] = *(const bf16x8*)(qp);
        qf[1] = *(const bf16x8*)(qp + 32);
    }

    f32x4 o[4];
    float mrow[4], lrow[4];
    #pragma unroll
    for (int i = 0; i < 4; ++i) { o[i] = (f32x4){0.f,0.f,0.f,0.f}; mrow[i] = -1e30f; lrow[i] = 0.f; }

    const int ntiles = qb + 1;
    for (int t = 0; t < ntiles; ++t) {
        const int kv0 = t * 64;

        // V reg-stage loads (issue before barrier; global only)
        u16x8 vv[2]; int vkey[2], vcc[2];
        #pragma unroll
        for (int ii = 0; ii < 2; ++ii) {
            int cid = tid + ii * 256;
            vkey[ii] = cid >> 3; vcc[ii] = cid & 7;
            vv[ii] = *(const u16x8*)(Vg + (size_t)(kv0 + vkey[ii]) * DD + vcc[ii] * 8);
        }

        __syncthreads();   // prior tile's LDS reads complete

        // K stage: 8 x 1KB global_load_lds; wave w issues instrs 2w, 2w+1.
        // Desired LDS content at byte key*128 + (chunk<<4 ^ (key&7)<<4):
        // K[key][chunk*8..+7]  -> per-lane source chunk = (l&7)^((l>>3)&7).
        #pragma unroll
        for (int ii = 0; ii < 2; ++ii) {
            const int instr = w * 2 + ii;
            const int rl = instr * 8 + (l >> 3);
            const int ch = (l & 7) ^ ((l >> 3) & 7);
            const u16* src = Kg + (size_t)(kv0 + rl) * DD + ch * 8;
            __builtin_amdgcn_global_load_lds((const __attribute__((address_space(1))) void*)src,
                (__attribute__((address_space(3))) void*)((char*)ldsK + instr * 1024), 16, 0, 0);
        }

        // V^T scattered writes: byte = d*128 + key*2, ^((((d>>3)^(d&7))&7)<<4)
        #pragma unroll
        for (int ii = 0; ii < 2; ++ii) {
            #pragma unroll
            for (int i = 0; i < 8; ++i) {
                const int d = vcc[ii] * 8 + i;
                const int swz = ((vcc[ii] ^ i) & 7) << 4;
                *(u16*)((char*)ldsVT + ((d * 128 + vkey[ii] * 2) ^ swz)) = (u16)vv[ii][i];
            }
        }
        __syncthreads();

        // ---- QK^T: S frags f (keys 16f+c), rows 4g+reg ----
        f32x4 s[4];
        #pragma unroll
        for (int f = 0; f < 4; ++f) {
            s[f] = (f32x4){0.f,0.f,0.f,0.f};
            #pragma unroll
            for (int hh = 0; hh < 2; ++hh) {
                const bf16x8 kf = *(const bf16x8*)((const char*)ldsK +
                    (16 * f + c) * 128 + ((((4 * hh + g) ^ (c & 7)) & 7) << 4));
                s[f] = __builtin_amdgcn_mfma_f32_16x16x32_bf16(qf[hh], kf, s[f], 0, 0, 0);
            }
        }

        // causal mask (diagonal tile only)
        if (t == qb) {
            #pragma unroll
            for (int f = 0; f < 4; ++f) {
                const int key_g = kv0 + 16 * f + c;
                #pragma unroll
                for (int r = 0; r < 4; ++r) {
                    const int q_g = q0 + w * 16 + 4 * g + r;
                    if (key_g > q_g) s[f][r] = -1e30f;
                }
            }
        }

        // ---- online softmax (fp32, exact) ----
        float rmax[4];
        #pragma unroll
        for (int r = 0; r < 4; ++r)
            rmax[r] = fmaxf(fmaxf(s[0][r], s[1][r]), fmaxf(s[2][r], s[3][r]));
        #pragma unroll
        for (int r = 0; r < 4; ++r) {
            #pragma unroll
            for (int msk = 1; msk < 16; msk <<= 1)
                rmax[r] = fmaxf(rmax[r], __shfl_xor(rmax[r], msk));
        }
        float corr[4];
        #pragma unroll
        for (int r = 0; r < 4; ++r) {
            const float mnew = fmaxf(mrow[r], rmax[r]);
            corr[r] = __expf(mrow[r] - mnew);
            mrow[r] = mnew;
            lrow[r] *= corr[r];
        }
        #pragma unroll
        for (int f = 0; f < 4; ++f)
            #pragma unroll
            for (int r = 0; r < 4; ++r) o[f][r] *= corr[r];

        float rsum[4] = {0.f, 0.f, 0.f, 0.f};
        #pragma unroll
        for (int f = 0; f < 4; ++f) {
            #pragma unroll
            for (int r = 0; r < 4; ++r) {
                const float p = __expf(s[f][r] - mrow[r]);
                rsum[r] += p;
                const int q_l = 4 * g + r, key_l = 16 * f + c;
                *(u16*)((char*)&ldsP[w][0] + ((q_l * 128 + key_l * 2) ^ ((q_l & 7) << 4))) = f2bf(p);
            }
        }
        #pragma unroll
        for (int r = 0; r < 4; ++r) {
            #pragma unroll
            for (int msk = 1; msk < 16; msk <<= 1)
                rsum[r] += __shfl_xor(rsum[r], msk);
            lrow[r] += rsum[r];
        }

        // ---- PV: O += P @ V ----
        #pragma unroll
        for (int hh = 0; hh < 2; ++hh) {
            const bf16x8 pf = *(const bf16x8*)((const char*)&ldsP[w][0] +
                c * 128 + ((((4 * hh + g) ^ (c & 7)) & 7) << 4));
            #pragma unroll
            for (int f = 0; f < 4; ++f) {
                const int d = 16 * f + c;
                const int swz = (((d >> 3) ^ (d & 7)) & 7) << 4;
                const bf16x8 vf = *(const bf16x8*)((const char*)ldsVT +
                    ((d * 128 + (32 * hh + 8 * g) * 2) ^ swz));
                o[f] = __builtin_amdgcn_mfma_f32_16x16x32_bf16(pf, vf, o[f], 0, 0, 0);
            }
        }
    }

    // epilogue: Y[b][q][h*64 + d] bf16
    #pragma unroll
    for (int f = 0; f < 4; ++f) {
        #pragma unroll
        for (int r = 0; r < 4; ++r) {
            const float val = o[f][r] / lrow[r];
            const int q_g = q0 + w * 16 + 4 * g + r;
            Y[((size_t)b * TT + q_g) * CC + h * DD + 16 * f + c] = f2bf(val);
        }
    }
}

// ---------------------------------------------------------------------------
extern "C" void kernel_launch(void* const* d_in, const int* in_sizes, int n_in,
                              void* d_out, int out_size, void* d_ws, size_t ws_size,
                              hipStream_t stream)
{
    const float* x      = (const float*)d_in[0];
    const float* W_attn = (const float*)d_in[1];
    const float* b_attn = (const float*)d_in[2];
    const float* W_proj = (const float*)d_in[3];
    const float* b_proj = (const float*)d_in[4];
    float* out = (float*)d_out;

    char* w = (char*)d_ws;
    u16* Qb = (u16*)w;  w += (size_t)BB * HH * TT * DD * 2;   // 8.39 MB
    u16* Kb = (u16*)w;  w += (size_t)BB * HH * TT * DD * 2;
    u16* Vb = (u16*)w;  w += (size_t)BB * HH * TT * DD * 2;
    u16* Xb = (u16*)w;  w += (size_t)BB * TT * CC * 2;        // 16.78 MB (aliases Yb)
    u16* WaT = (u16*)w; w += (size_t)CC * 3 * CC * 2;
    u16* WpT = (u16*)w; w += (size_t)CC * CC * 2;
    u16* Yb = Xb;

    const dim3 blk(256);

    cast_bf16<<<2048, blk, 0, stream>>>(x, Xb, BB * TT * CC / 4);
    transpose_cast<<<dim3(3 * CC / 32, CC / 32), blk, 0, stream>>>(W_attn, WaT, CC, 3 * CC);
    transpose_cast<<<dim3(CC / 32, CC / 32), blk, 0, stream>>>(W_proj, WpT, CC, CC);

    gemm_bf16<1><<<dim3(3 * CC / 128, BB * TT / 128), blk, 0, stream>>>(
        Xb, WaT, b_attn, nullptr, Qb, Kb, Vb, BB * TT, 3 * CC, CC);

    mfma_attn<<<dim3(TT / 64, BB * HH), blk, 0, stream>>>(Qb, Kb, Vb, Yb);

    gemm_bf16<0><<<dim3(CC / 128, BB * TT / 128), blk, 0, stream>>>(
        Yb, WpT, b_proj, out, nullptr, nullptr, nullptr, BB * TT, CC, CC);
}

// Round 8
// 358.951 us; speedup vs baseline: 9.2739x; 1.2775x over previous
//
#include <hip/hip_runtime.h>

// Causal self-attention: x -> qkv GEMM (bf16 MFMA, scatters bf16 Q/K/V) ->
// MFMA flash attention (persistent blocks + dynamic work queue) -> proj GEMM.
// B=4, T=2048, C=1024, H=16, D=64.

typedef unsigned short u16;
typedef unsigned int   u32;
typedef short bf16x8 __attribute__((ext_vector_type(8)));
typedef float f32x4  __attribute__((ext_vector_type(4)));
typedef u16   u16x8  __attribute__((ext_vector_type(8)));

constexpr int BB = 4;
constexpr int TT = 2048;
constexpr int CC = 1024;
constexpr int HH = 16;
constexpr int DD = 64;

// Q pre-scale: 1/sqrt(64) * log2(e)  -> softmax computed in exp2 space (exact)
#define QSCALE 0.1803368801111244f

__device__ __forceinline__ u16 f2bf(float f) {
    u32 x = __float_as_uint(f);
    x += 0x7FFFu + ((x >> 16) & 1u);
    return (u16)(x >> 16);
}

// ---------------------------------------------------------------------------
__global__ __launch_bounds__(256)
void cast_bf16(const float* __restrict__ in, u16* __restrict__ out, int n4) {
    int i = blockIdx.x * blockDim.x + threadIdx.x;
    const int stride = gridDim.x * blockDim.x;
    for (; i < n4; i += stride) {
        float4 v = reinterpret_cast<const float4*>(in)[i];
        ushort4 o;
        o.x = f2bf(v.x); o.y = f2bf(v.y); o.z = f2bf(v.z); o.w = f2bf(v.w);
        reinterpret_cast<ushort4*>(out)[i] = o;
    }
}

__global__ __launch_bounds__(256)
void transpose_cast(const float* __restrict__ in, u16* __restrict__ out,
                    int K, int N) {
    __shared__ u16 tile[32][33];
    const int n0 = blockIdx.x * 32, k0 = blockIdx.y * 32;
    const int tx = threadIdx.x & 31, ty = threadIdx.x >> 5;
    #pragma unroll
    for (int r = 0; r < 32; r += 8)
        tile[tx][ty + r] = f2bf(in[(size_t)(k0 + ty + r) * N + n0 + tx]);
    __syncthreads();
    #pragma unroll
    for (int r = 0; r < 32; r += 8)
        out[(size_t)(n0 + ty + r) * K + k0 + tx] = tile[ty + r][tx];
}

__global__ void zero_ctr(u32* c) { *c = 0u; }

// ---------------------------------------------------------------------------
// bf16 MFMA GEMM (m97 structure, 128x128, BK=32).  MODE 0: fp32 C out.
// MODE 1: scatter bf16 into Qw/Kw/Vw [B*H][T][D]; Q scaled by QSCALE.
// ---------------------------------------------------------------------------
template<int MODE>
__global__ __launch_bounds__(256)
void gemm_bf16(const u16* __restrict__ A, const u16* __restrict__ Bt,
               const float* __restrict__ bias, float* __restrict__ Cout,
               u16* __restrict__ Qw, u16* __restrict__ Kw,
               u16* __restrict__ Vw, int M, int N, int K)
{
    constexpr int BM = 128, BN = 128, BK = 32;
    __shared__ __align__(16) u16 ldsA[BM * BK];
    __shared__ __align__(16) u16 ldsB[BN * BK];

    const int tid  = threadIdx.x;
    const int wave = tid >> 6, lane = tid & 63;
    const int wm = wave >> 1, wn = wave & 1;
    const int n0 = blockIdx.x * BN, m0 = blockIdx.y * BM;

    const int srow = lane >> 2, skq = lane & 3;
    const char* gA = (const char*)(A  + (size_t)(m0 + wave * 32 + srow) * K) + skq * 16;
    const char* gB = (const char*)(Bt + (size_t)(n0 + wave * 32 + srow) * K) + skq * 16;
    char* lA = (char*)ldsA + wave * 2048;
    char* lB = (char*)ldsB + wave * 2048;
    const size_t rowskip = (size_t)16 * K * 2;

    f32x4 acc[4][4];
    #pragma unroll
    for (int i = 0; i < 4; ++i)
        #pragma unroll
        for (int j = 0; j < 4; ++j) acc[i][j] = (f32x4){0.f, 0.f, 0.f, 0.f};

    const int fr = lane & 15, kq = lane >> 4;
    const char* rdA = (const char*)ldsA + (wm * 64 + fr) * 64 + kq * 16;
    const char* rdB = (const char*)ldsB + (wn * 64 + fr) * 64 + kq * 16;

    for (int k0 = 0; k0 < K; k0 += BK) {
        const char* ga = gA + (size_t)k0 * 2;
        const char* gb = gB + (size_t)k0 * 2;
        __builtin_amdgcn_global_load_lds((const __attribute__((address_space(1))) void*)ga,
                                         (__attribute__((address_space(3))) void*)lA, 16, 0, 0);
        __builtin_amdgcn_global_load_lds((const __attribute__((address_space(1))) void*)(ga + rowskip),
                                         (__attribute__((address_space(3))) void*)(lA + 1024), 16, 0, 0);
        __builtin_amdgcn_global_load_lds((const __attribute__((address_space(1))) void*)gb,
                                         (__attribute__((address_space(3))) void*)lB, 16, 0, 0);
        __builtin_amdgcn_global_load_lds((const __attribute__((address_space(1))) void*)(gb + rowskip),
                                         (__attribute__((address_space(3))) void*)(lB + 1024), 16, 0, 0);
        __syncthreads();

        bf16x8 af[4], bfv[4];
        #pragma unroll
        for (int f = 0; f < 4; ++f) af[f]  = *(const bf16x8*)(rdA + f * 1024);
        #pragma unroll
        for (int f = 0; f < 4; ++f) bfv[f] = *(const bf16x8*)(rdB + f * 1024);
        #pragma unroll
        for (int i = 0; i < 4; ++i)
            #pragma unroll
            for (int j = 0; j < 4; ++j)
                acc[i][j] = __builtin_amdgcn_mfma_f32_16x16x32_bf16(af[i], bfv[j], acc[i][j], 0, 0, 0);
        __syncthreads();
    }

    #pragma unroll
    for (int i = 0; i < 4; ++i) {
        const int mbase = m0 + wm * 64 + i * 16 + (lane >> 4) * 4;
        #pragma unroll
        for (int j = 0; j < 4; ++j) {
            const int n = n0 + wn * 64 + j * 16 + (lane & 15);
            const float bv = bias[n];
            #pragma unroll
            for (int r = 0; r < 4; ++r) {
                const int m = mbase + r;
                const float val = acc[i][j][r] + bv;
                if (MODE == 0) {
                    Cout[(size_t)m * N + n] = val;
                } else {
                    const int which = n >> 10;        // 0=q 1=k 2=v
                    const int rr = n & 1023;
                    const int hh = rr >> 6, dd = rr & 63;
                    const int bb = m >> 11, tt = m & 2047;
                    u16* dst = (which == 0 ? Qw : which == 1 ? Kw : Vw);
                    const float v2 = (which == 0) ? val * QSCALE : val;
                    dst[((size_t)(bb * HH + hh) * TT + tt) * DD + dd] = f2bf(v2);
                }
            }
        }
    }
}

// ---------------------------------------------------------------------------
// MFMA flash attention (causal), persistent blocks + dynamic work queue.
// Work item j: qb = 31 - j/64 (longest first), bh = j%64. 2048 items.
// Per item: 64 q-rows (4 waves x 16), KV tiles of 64, exp2-space softmax
// with defer-max rescale. All LDS layouts XOR-swizzled, conflict-balanced.
// ---------------------------------------------------------------------------
__global__ __launch_bounds__(256, 4)
void mfma_attn(const u16* __restrict__ Q, const u16* __restrict__ K,
               const u16* __restrict__ V, u16* __restrict__ Y,
               u32* __restrict__ ctr)
{
    const int tid = threadIdx.x, w = tid >> 6, l = tid & 63;
    const int g = l >> 4, c = l & 15;

    __shared__ __align__(16) u16 ldsK[64 * 64];    // [key][d], swizzled
    __shared__ __align__(16) u16 ldsVT[64 * 64];   // [d][key], swizzled
    __shared__ __align__(16) u16 ldsP[4][16 * 64]; // per-wave [q][key], swizzled
    __shared__ int s_item;

    for (;;) {
        if (tid == 0) s_item = (int)atomicAdd(ctr, 1u);
        __syncthreads();                 // broadcast + order prev item's LDS reads
        const int item = s_item;
        if (item >= 2048) break;

        const int qb = 31 - (item >> 6);        // longest first
        const int bh = item & 63;
        const int b = bh >> 4, h = bh & 15;
        const int q0 = qb * 64;

        const u16* Qg = Q + (size_t)bh * TT * DD;
        const u16* Kg = K + (size_t)bh * TT * DD;
        const u16* Vg = V + (size_t)bh * TT * DD;

        // Q A-frags: row(m)=c -> q0+16w+c; k(d) = 32*hh + 8g + i
        bf16x8 qf[2];
        {
            const u16* qp = Qg + (size_t)(q0 + w * 16 + c) * DD + g * 8;
            qf[0] = *(const bf16x8*)(qp);
            qf[1] = *(const bf16x8*)(qp + 32);
        }

        f32x4 o[4];
        float mrow[4], lrow[4];
        #pragma unroll
        for (int i = 0; i < 4; ++i) { o[i] = (f32x4){0.f,0.f,0.f,0.f}; mrow[i] = -1e30f; lrow[i] = 0.f; }

        const int ntiles = qb + 1;
        for (int t = 0; t < ntiles; ++t) {
            const int kv0 = t * 64;

            // V reg-stage loads (global only, before barrier)
            u16x8 vv[2]; int vkey[2], vcc[2];
            #pragma unroll
            for (int ii = 0; ii < 2; ++ii) {
                int cid = tid + ii * 256;
                vkey[ii] = cid >> 3; vcc[ii] = cid & 7;
                vv[ii] = *(const u16x8*)(Vg + (size_t)(kv0 + vkey[ii]) * DD + vcc[ii] * 8);
            }

            __syncthreads();   // prior tile's LDS reads complete

            // K stage: 8 x 1KB global_load_lds, pre-swizzled source
            #pragma unroll
            for (int ii = 0; ii < 2; ++ii) {
                const int instr = w * 2 + ii;
                const int rl = instr * 8 + (l >> 3);
                const int ch = (l & 7) ^ ((l >> 3) & 7);
                const u16* src = Kg + (size_t)(kv0 + rl) * DD + ch * 8;
                __builtin_amdgcn_global_load_lds((const __attribute__((address_space(1))) void*)src,
                    (__attribute__((address_space(3))) void*)((char*)ldsK + instr * 1024), 16, 0, 0);
            }

            // V^T scattered writes
            #pragma unroll
            for (int ii = 0; ii < 2; ++ii) {
                #pragma unroll
                for (int i = 0; i < 8; ++i) {
                    const int d = vcc[ii] * 8 + i;
                    const int swz = ((vcc[ii] ^ i) & 7) << 4;
                    *(u16*)((char*)ldsVT + ((d * 128 + vkey[ii] * 2) ^ swz)) = (u16)vv[ii][i];
                }
            }
            __syncthreads();

            // ---- QK^T ----
            f32x4 s[4];
            #pragma unroll
            for (int f = 0; f < 4; ++f) {
                s[f] = (f32x4){0.f,0.f,0.f,0.f};
                #pragma unroll
                for (int hh = 0; hh < 2; ++hh) {
                    const bf16x8 kf = *(const bf16x8*)((const char*)ldsK +
                        (16 * f + c) * 128 + ((((4 * hh + g) ^ (c & 7)) & 7) << 4));
                    s[f] = __builtin_amdgcn_mfma_f32_16x16x32_bf16(qf[hh], kf, s[f], 0, 0, 0);
                }
            }

            // causal mask (diagonal tile only; first processed tile per item)
            if (t == qb) {
                #pragma unroll
                for (int f = 0; f < 4; ++f) {
                    const int key_g = kv0 + 16 * f + c;
                    #pragma unroll
                    for (int r = 0; r < 4; ++r) {
                        const int q_g = q0 + w * 16 + 4 * g + r;
                        if (key_g > q_g) s[f][r] = -1e30f;
                    }
                }
            }

            // ---- online softmax (exp2 space, exact; defer-max rescale) ----
            float rmax[4];
            #pragma unroll
            for (int r = 0; r < 4; ++r)
                rmax[r] = fmaxf(fmaxf(s[0][r], s[1][r]), fmaxf(s[2][r], s[3][r]));
            #pragma unroll
            for (int r = 0; r < 4; ++r) {
                #pragma unroll
                for (int msk = 1; msk < 16; msk <<= 1)
                    rmax[r] = fmaxf(rmax[r], __shfl_xor(rmax[r], msk));
            }
            bool need = (rmax[0] > mrow[0] + 8.f) | (rmax[1] > mrow[1] + 8.f) |
                        (rmax[2] > mrow[2] + 8.f) | (rmax[3] > mrow[3] + 8.f);
            if (__any(need)) {
                #pragma unroll
                for (int r = 0; r < 4; ++r) {
                    const float mnew = fmaxf(mrow[r], rmax[r]);
                    const float corr = exp2f(mrow[r] - mnew);
                    mrow[r] = mnew;
                    lrow[r] *= corr;
                    #pragma unroll
                    for (int f = 0; f < 4; ++f) o[f][r] *= corr;
                }
            }

            float rsum[4] = {0.f, 0.f, 0.f, 0.f};
            #pragma unroll
            for (int f = 0; f < 4; ++f) {
                #pragma unroll
                for (int r = 0; r < 4; ++r) {
                    const float p = exp2f(s[f][r] - mrow[r]);   // bounded by 2^8
                    rsum[r] += p;
                    const int q_l = 4 * g + r, key_l = 16 * f + c;
                    *(u16*)((char*)&ldsP[w][0] + ((q_l * 128 + key_l * 2) ^ ((q_l & 7) << 4))) = f2bf(p);
                }
            }
            #pragma unroll
            for (int r = 0; r < 4; ++r) {
                #pragma unroll
                for (int msk = 1; msk < 16; msk <<= 1)
                    rsum[r] += __shfl_xor(rsum[r], msk);
                lrow[r] += rsum[r];
            }

            // ---- PV: O += P @ V ----
            #pragma unroll
            for (int hh = 0; hh < 2; ++hh) {
                const bf16x8 pf = *(const bf16x8*)((const char*)&ldsP[w][0] +
                    c * 128 + ((((4 * hh + g) ^ (c & 7)) & 7) << 4));
                #pragma unroll
                for (int f = 0; f < 4; ++f) {
                    const int d = 16 * f + c;
                    const int swz = (((d >> 3) ^ (d & 7)) & 7) << 4;
                    const bf16x8 vf = *(const bf16x8*)((const char*)ldsVT +
                        ((d * 128 + (32 * hh + 8 * g) * 2) ^ swz));
                    o[f] = __builtin_amdgcn_mfma_f32_16x16x32_bf16(pf, vf, o[f], 0, 0, 0);
                }
            }
        }

        // epilogue: Y[b][q][h*64 + d] bf16
        #pragma unroll
        for (int f = 0; f < 4; ++f) {
            #pragma unroll
            for (int r = 0; r < 4; ++r) {
                const float val = o[f][r] / lrow[r];
                const int q_g = q0 + w * 16 + 4 * g + r;
                Y[((size_t)b * TT + q_g) * CC + h * DD + 16 * f + c] = f2bf(val);
            }
        }
    }
}

// ---------------------------------------------------------------------------
extern "C" void kernel_launch(void* const* d_in, const int* in_sizes, int n_in,
                              void* d_out, int out_size, void* d_ws, size_t ws_size,
                              hipStream_t stream)
{
    const float* x      = (const float*)d_in[0];
    const float* W_attn = (const float*)d_in[1];
    const float* b_attn = (const float*)d_in[2];
    const float* W_proj = (const float*)d_in[3];
    const float* b_proj = (const float*)d_in[4];
    float* out = (float*)d_out;

    char* w = (char*)d_ws;
    u16* Qb = (u16*)w;  w += (size_t)BB * HH * TT * DD * 2;   // 8.39 MB
    u16* Kb = (u16*)w;  w += (size_t)BB * HH * TT * DD * 2;
    u16* Vb = (u16*)w;  w += (size_t)BB * HH * TT * DD * 2;
    u16* Xb = (u16*)w;  w += (size_t)BB * TT * CC * 2;        // 16.78 MB (aliases Yb)
    u16* WaT = (u16*)w; w += (size_t)CC * 3 * CC * 2;
    u16* WpT = (u16*)w; w += (size_t)CC * CC * 2;
    u32* ctr = (u32*)w; w += 256;                              // work-queue counter
    u16* Yb = Xb;

    const dim3 blk(256);

    cast_bf16<<<2048, blk, 0, stream>>>(x, Xb, BB * TT * CC / 4);
    transpose_cast<<<dim3(3 * CC / 32, CC / 32), blk, 0, stream>>>(W_attn, WaT, CC, 3 * CC);
    transpose_cast<<<dim3(CC / 32, CC / 32), blk, 0, stream>>>(W_proj, WpT, CC, CC);
    zero_ctr<<<1, 1, 0, stream>>>(ctr);

    gemm_bf16<1><<<dim3(3 * CC / 128, BB * TT / 128), blk, 0, stream>>>(
        Xb, WaT, b_attn, nullptr, Qb, Kb, Vb, BB * TT, 3 * CC, CC);

    mfma_attn<<<dim3(1024), blk, 0, stream>>>(Qb, Kb, Vb, Yb, ctr);

    gemm_bf16<0><<<dim3(CC / 128, BB * TT / 128), blk, 0, stream>>>(
        Yb, WpT, b_proj, out, nullptr, nullptr, nullptr, BB * TT, CC, CC);
}

// Round 10
// 314.694 us; speedup vs baseline: 10.5782x; 1.1406x over previous
//
#include <hip/hip_runtime.h>

// Causal self-attention: x -> qkv GEMM (bf16 MFMA, scatters bf16 Q/K/V) ->
// MFMA flash attention v3 (32 rows/wave, swapped QK^T, in-register P) ->
// proj GEMM.  B=4, T=2048, C=1024, H=16, D=64.

typedef unsigned short u16;
typedef unsigned int   u32;
typedef short bf16x8 __attribute__((ext_vector_type(8)));
typedef float f32x4  __attribute__((ext_vector_type(4)));
typedef u16   u16x8  __attribute__((ext_vector_type(8)));
typedef u32   u32x4  __attribute__((ext_vector_type(4)));

constexpr int BB = 4;
constexpr int TT = 2048;
constexpr int CC = 1024;
constexpr int HH = 16;
constexpr int DD = 64;

// Q pre-scale: 1/sqrt(64) * log2(e) -> softmax in exp2 space (exact)
#define QSCALE 0.1803368801111244f

__device__ __forceinline__ u16 f2bf(float f) {
    u32 x = __float_as_uint(f);
    x += 0x7FFFu + ((x >> 16) & 1u);
    return (u16)(x >> 16);
}

__device__ __forceinline__ u32 cvt_pk_bf16(float lo, float hi) {
    u32 r;
    asm("v_cvt_pk_bf16_f32 %0, %1, %2" : "=v"(r) : "v"(lo), "v"(hi));
    return r;
}

// ---------------------------------------------------------------------------
__global__ __launch_bounds__(256)
void cast_bf16(const float* __restrict__ in, u16* __restrict__ out, int n4) {
    int i = blockIdx.x * blockDim.x + threadIdx.x;
    const int stride = gridDim.x * blockDim.x;
    for (; i < n4; i += stride) {
        float4 v = reinterpret_cast<const float4*>(in)[i];
        ushort4 o;
        o.x = f2bf(v.x); o.y = f2bf(v.y); o.z = f2bf(v.z); o.w = f2bf(v.w);
        reinterpret_cast<ushort4*>(out)[i] = o;
    }
}

__global__ __launch_bounds__(256)
void transpose_cast(const float* __restrict__ in, u16* __restrict__ out,
                    int K, int N) {
    __shared__ u16 tile[32][33];
    const int n0 = blockIdx.x * 32, k0 = blockIdx.y * 32;
    const int tx = threadIdx.x & 31, ty = threadIdx.x >> 5;
    #pragma unroll
    for (int r = 0; r < 32; r += 8)
        tile[tx][ty + r] = f2bf(in[(size_t)(k0 + ty + r) * N + n0 + tx]);
    __syncthreads();
    #pragma unroll
    for (int r = 0; r < 32; r += 8)
        out[(size_t)(n0 + ty + r) * K + k0 + tx] = tile[ty + r][tx];
}

// ---------------------------------------------------------------------------
// bf16 MFMA GEMM (m97 structure, 128x128, BK=32).  MODE 0: fp32 C out.
// MODE 1: scatter bf16 into Qw/Kw/Vw [B*H][T][D]; Q scaled by QSCALE.
// ---------------------------------------------------------------------------
template<int MODE>
__global__ __launch_bounds__(256)
void gemm_bf16(const u16* __restrict__ A, const u16* __restrict__ Bt,
               const float* __restrict__ bias, float* __restrict__ Cout,
               u16* __restrict__ Qw, u16* __restrict__ Kw,
               u16* __restrict__ Vw, int M, int N, int K)
{
    constexpr int BM = 128, BN = 128, BK = 32;
    __shared__ __align__(16) u16 ldsA[BM * BK];
    __shared__ __align__(16) u16 ldsB[BN * BK];

    const int tid  = threadIdx.x;
    const int wave = tid >> 6, lane = tid & 63;
    const int wm = wave >> 1, wn = wave & 1;
    const int n0 = blockIdx.x * BN, m0 = blockIdx.y * BM;

    const int srow = lane >> 2, skq = lane & 3;
    const char* gA = (const char*)(A  + (size_t)(m0 + wave * 32 + srow) * K) + skq * 16;
    const char* gB = (const char*)(Bt + (size_t)(n0 + wave * 32 + srow) * K) + skq * 16;
    char* lA = (char*)ldsA + wave * 2048;
    char* lB = (char*)ldsB + wave * 2048;
    const size_t rowskip = (size_t)16 * K * 2;

    f32x4 acc[4][4];
    #pragma unroll
    for (int i = 0; i < 4; ++i)
        #pragma unroll
        for (int j = 0; j < 4; ++j) acc[i][j] = (f32x4){0.f, 0.f, 0.f, 0.f};

    const int fr = lane & 15, kq = lane >> 4;
    const char* rdA = (const char*)ldsA + (wm * 64 + fr) * 64 + kq * 16;
    const char* rdB = (const char*)ldsB + (wn * 64 + fr) * 64 + kq * 16;

    for (int k0 = 0; k0 < K; k0 += BK) {
        const char* ga = gA + (size_t)k0 * 2;
        const char* gb = gB + (size_t)k0 * 2;
        __builtin_amdgcn_global_load_lds((const __attribute__((address_space(1))) void*)ga,
                                         (__attribute__((address_space(3))) void*)lA, 16, 0, 0);
        __builtin_amdgcn_global_load_lds((const __attribute__((address_space(1))) void*)(ga + rowskip),
                                         (__attribute__((address_space(3))) void*)(lA + 1024), 16, 0, 0);
        __builtin_amdgcn_global_load_lds((const __attribute__((address_space(1))) void*)gb,
                                         (__attribute__((address_space(3))) void*)lB, 16, 0, 0);
        __builtin_amdgcn_global_load_lds((const __attribute__((address_space(1))) void*)(gb + rowskip),
                                         (__attribute__((address_space(3))) void*)(lB + 1024), 16, 0, 0);
        __syncthreads();

        bf16x8 af[4], bfv[4];
        #pragma unroll
        for (int f = 0; f < 4; ++f) af[f]  = *(const bf16x8*)(rdA + f * 1024);
        #pragma unroll
        for (int f = 0; f < 4; ++f) bfv[f] = *(const bf16x8*)(rdB + f * 1024);
        #pragma unroll
        for (int i = 0; i < 4; ++i)
            #pragma unroll
            for (int j = 0; j < 4; ++j)
                acc[i][j] = __builtin_amdgcn_mfma_f32_16x16x32_bf16(af[i], bfv[j], acc[i][j], 0, 0, 0);
        __syncthreads();
    }

    #pragma unroll
    for (int i = 0; i < 4; ++i) {
        const int mbase = m0 + wm * 64 + i * 16 + (lane >> 4) * 4;
        #pragma unroll
        for (int j = 0; j < 4; ++j) {
            const int n = n0 + wn * 64 + j * 16 + (lane & 15);
            const float bv = bias[n];
            #pragma unroll
            for (int r = 0; r < 4; ++r) {
                const int m = mbase + r;
                const float val = acc[i][j][r] + bv;
                if (MODE == 0) {
                    Cout[(size_t)m * N + n] = val;
                } else {
                    const int which = n >> 10;        // 0=q 1=k 2=v
                    const int rr = n & 1023;
                    const int hh = rr >> 6, dd = rr & 63;
                    const int bb = m >> 11, tt = m & 2047;
                    u16* dst = (which == 0 ? Qw : which == 1 ? Kw : Vw);
                    const float v2 = (which == 0) ? val * QSCALE : val;
                    dst[((size_t)(bb * HH + hh) * TT + tt) * DD + dd] = f2bf(v2);
                }
            }
        }
    }
}

// ---------------------------------------------------------------------------
// MFMA flash attention v3 (causal). Q,K,V bf16 [B*H][T][D], Y bf16 [B][T][C].
// Block: 128 threads = 2 waves, each wave 32 q-rows (2 row-windows rg).
// Grid: 2048 variable-length blocks, longest-first (HW dispatcher = LPT
// queue); bh = ((bid&7)<<3)|((bid>>3)&7) pins bh-octets to XCD L2.
// QK^T swapped: S^T = mfma(K, Q) -> col=q per lane -> softmax per-lane
// (exp2-space, exact, defer-max). P converted via v_cvt_pk_bf16_f32 and
// redistributed in-register by a 2-step butterfly (bit-permutation
// lane(g1,g0),reg(f1,f0,h) -> lane(f0,g1),reg(f1,g0,h)) to feed PV's
// A-operand. No P LDS. K LDS via pre-swizzled global_load_lds; V^T LDS
// swizzled scatter (round-7/8-verified layouts).
// launch_bounds(128,3): VGPR budget ~170 — live state ~130-150 regs; a
// (128,4)=128-reg cap would force scratch spill (worse than 3 waves/SIMD).
// ---------------------------------------------------------------------------
__global__ __launch_bounds__(128, 3)
void mfma_attn(const u16* __restrict__ Q, const u16* __restrict__ K,
               const u16* __restrict__ V, u16* __restrict__ Y)
{
    const int bid = blockIdx.x;
    const int qb = 31 - (bid >> 6);                 // longest first
    const int b6 = bid & 63;
    const int bh = ((b6 & 7) << 3) | (b6 >> 3);     // XCD-pinned bh octet
    const int b = bh >> 4, h = bh & 15;
    const int q0 = qb * 64;
    const int tid = threadIdx.x, w = tid >> 6, ln = tid & 63;
    const int g = ln >> 4, c = ln & 15;
    const bool hi5 = (ln & 32) != 0, hi4 = (ln & 16) != 0;

    __shared__ __align__(16) u16 ldsK[64 * 64];    // [key][d], swizzled
    __shared__ __align__(16) u16 ldsVT[64 * 64];   // [d][key], swizzled

    const u16* Qg = Q + (size_t)bh * TT * DD;
    const u16* Kg = K + (size_t)bh * TT * DD;
    const u16* Vg = V + (size_t)bh * TT * DD;

    // Q B-frags: q = q0 + 32w + 16rg + c; k(d) = 32hh + 8g + i
    bf16x8 qf[2][2];
    #pragma unroll
    for (int rg = 0; rg < 2; ++rg) {
        const u16* qp = Qg + (size_t)(q0 + w * 32 + rg * 16 + c) * DD + g * 8;
        qf[rg][0] = *(const bf16x8*)(qp);
        qf[rg][1] = *(const bf16x8*)(qp + 32);
    }

    f32x4 o[2][4];
    float m[2], lsum[2];
    #pragma unroll
    for (int rg = 0; rg < 2; ++rg) {
        m[rg] = -1e30f; lsum[rg] = 0.f;
        #pragma unroll
        for (int f = 0; f < 4; ++f) o[rg][f] = (f32x4){0.f,0.f,0.f,0.f};
    }

    const int ntiles = qb + 1;
    for (int t = 0; t < ntiles; ++t) {
        const int kv0 = t * 64;

        // V reg-stage loads (global only, before barrier): 4 x 16B/thread
        u16x8 vv[4]; int vkey[4], vcc[4];
        #pragma unroll
        for (int ii = 0; ii < 4; ++ii) {
            int cid = tid + ii * 128;
            vkey[ii] = cid >> 3; vcc[ii] = cid & 7;
            vv[ii] = *(const u16x8*)(Vg + (size_t)(kv0 + vkey[ii]) * DD + vcc[ii] * 8);
        }

        __syncthreads();   // prior tile's LDS reads complete

        // K stage: 8 x 1KB global_load_lds, pre-swizzled source; wave w: 4
        #pragma unroll
        for (int ii = 0; ii < 4; ++ii) {
            const int instr = w * 4 + ii;
            const int rl = instr * 8 + (ln >> 3);
            const int ch = (ln & 7) ^ ((ln >> 3) & 7);
            const u16* src = Kg + (size_t)(kv0 + rl) * DD + ch * 8;
            __builtin_amdgcn_global_load_lds((const __attribute__((address_space(1))) void*)src,
                (__attribute__((address_space(3))) void*)((char*)ldsK + instr * 1024), 16, 0, 0);
        }

        // V^T scattered writes: byte = d*128 + key*2, ^((((d>>3)^(d&7))&7)<<4)
        #pragma unroll
        for (int ii = 0; ii < 4; ++ii) {
            #pragma unroll
            for (int i = 0; i < 8; ++i) {
                const int d = vcc[ii] * 8 + i;
                const int swz = ((vcc[ii] ^ i) & 7) << 4;
                *(u16*)((char*)ldsVT + ((d * 128 + vkey[ii] * 2) ^ swz)) = (u16)vv[ii][i];
            }
        }
        __syncthreads();

        // ---- QK^T (swapped): s[rg][f] = S^T, col=q(c), row=key(16f+4g+r)
        f32x4 s[2][4];
        #pragma unroll
        for (int rg = 0; rg < 2; ++rg)
            #pragma unroll
            for (int f = 0; f < 4; ++f) s[rg][f] = (f32x4){0.f,0.f,0.f,0.f};
        #pragma unroll
        for (int f = 0; f < 4; ++f) {
            #pragma unroll
            for (int hh = 0; hh < 2; ++hh) {
                const bf16x8 kf = *(const bf16x8*)((const char*)ldsK +
                    (16 * f + c) * 128 + ((((4 * hh + g) ^ (c & 7)) & 7) << 4));
                #pragma unroll
                for (int rg = 0; rg < 2; ++rg)
                    s[rg][f] = __builtin_amdgcn_mfma_f32_16x16x32_bf16(kf, qf[rg][hh], s[rg][f], 0, 0, 0);
            }
        }

        // causal mask (diagonal tile only): mask key > q
        if (t == qb) {
            #pragma unroll
            for (int rg = 0; rg < 2; ++rg) {
                const int q_g = q0 + w * 32 + rg * 16 + c;
                #pragma unroll
                for (int f = 0; f < 4; ++f)
                    #pragma unroll
                    for (int r = 0; r < 4; ++r)
                        if (kv0 + 16 * f + 4 * g + r > q_g) s[rg][f][r] = -1e30f;
            }
        }

        // ---- softmax (per-lane, exp2-space, exact, defer-max) ----
        float rmax[2];
        #pragma unroll
        for (int rg = 0; rg < 2; ++rg) {
            float mx = s[rg][0][0];
            #pragma unroll
            for (int f = 0; f < 4; ++f)
                #pragma unroll
                for (int r = 0; r < 4; ++r) mx = fmaxf(mx, s[rg][f][r]);
            mx = fmaxf(mx, __shfl_xor(mx, 16));
            mx = fmaxf(mx, __shfl_xor(mx, 32));
            rmax[rg] = mx;
        }
        const bool need = (rmax[0] > m[0] + 8.f) || (rmax[1] > m[1] + 8.f);
        if (__any(need)) {
            #pragma unroll
            for (int rg = 0; rg < 2; ++rg) {
                const float mn = fmaxf(m[rg], rmax[rg]);
                const float cst = exp2f(m[rg] - mn);
                m[rg] = mn;
                lsum[rg] *= cst;
                #pragma unroll
                for (int r = 0; r < 4; ++r) {
                    const float cr = __shfl(cst, (ln & 48) | (4 * g + r));
                    #pragma unroll
                    for (int f = 0; f < 4; ++f) o[rg][f][r] *= cr;
                }
            }
        }

        bf16x8 pa[2][2];
        #pragma unroll
        for (int rg = 0; rg < 2; ++rg) {
            float rs = 0.f;
            #pragma unroll
            for (int f = 0; f < 4; ++f)
                #pragma unroll
                for (int r = 0; r < 4; ++r) {
                    const float p = exp2f(s[rg][f][r] - m[rg]);   // <= 2^8
                    s[rg][f][r] = p;
                    rs += p;
                }
            rs += __shfl_xor(rs, 16);
            rs += __shfl_xor(rs, 32);
            lsum[rg] += rs;

            // pack: W[4*(f>>1) + 2*(f&1) + h] = pk(p[f][2h], p[f][2h+1])
            u32 W[8];
            #pragma unroll
            for (int f = 0; f < 4; ++f) {
                const int base = 4 * (f >> 1) + 2 * (f & 1);
                W[base + 0] = cvt_pk_bf16(s[rg][f][0], s[rg][f][1]);
                W[base + 1] = cvt_pk_bf16(s[rg][f][2], s[rg][f][3]);
            }
            // exchange T1' (lane-bit5 <-> reg-bit1), T2' (lane-bit4 <-> reg-bit1)
            #pragma unroll
            for (int pi = 0; pi < 4; ++pi) {
                const int i = (pi & 1) | ((pi >> 1) << 2);   // 0,1,4,5
                u32 snd = hi5 ? W[i] : W[i + 2];
                u32 rcv = __shfl_xor(snd, 32);
                u32 na = hi5 ? rcv : W[i];
                u32 nb = hi5 ? W[i + 2] : rcv;
                W[i] = na; W[i + 2] = nb;
            }
            #pragma unroll
            for (int pi = 0; pi < 4; ++pi) {
                const int i = (pi & 1) | ((pi >> 1) << 2);
                u32 snd = hi4 ? W[i] : W[i + 2];
                u32 rcv = __shfl_xor(snd, 16);
                u32 na = hi4 ? rcv : W[i];
                u32 nb = hi4 ? W[i + 2] : rcv;
                W[i] = na; W[i + 2] = nb;
            }
            u32x4 w0 = {W[0], W[1], W[2], W[3]};
            u32x4 w1 = {W[4], W[5], W[6], W[7]};
            pa[rg][0] = __builtin_bit_cast(bf16x8, w0);
            pa[rg][1] = __builtin_bit_cast(bf16x8, w1);
        }

        // ---- PV: O += P @ V (vf shared across rg) ----
        #pragma unroll
        for (int hh = 0; hh < 2; ++hh) {
            #pragma unroll
            for (int f = 0; f < 4; ++f) {
                const int d = 16 * f + c;
                const int swz = (((d >> 3) ^ (d & 7)) & 7) << 4;
                const bf16x8 vf = *(const bf16x8*)((const char*)ldsVT +
                    ((d * 128 + (32 * hh + 8 * g) * 2) ^ swz));
                #pragma unroll
                for (int rg = 0; rg < 2; ++rg)
                    o[rg][f] = __builtin_amdgcn_mfma_f32_16x16x32_bf16(pa[rg][hh], vf, o[rg][f], 0, 0, 0);
            }
        }
    }

    // epilogue: Y[b][q][h*64 + d] bf16
    #pragma unroll
    for (int rg = 0; rg < 2; ++rg) {
        #pragma unroll
        for (int r = 0; r < 4; ++r) {
            const float lr = __shfl(lsum[rg], (ln & 48) | (4 * g + r));
            const float inv = 1.f / lr;
            const int q_g = q0 + w * 32 + rg * 16 + 4 * g + r;
            #pragma unroll
            for (int f = 0; f < 4; ++f)
                Y[((size_t)b * TT + q_g) * CC + h * DD + 16 * f + c] = f2bf(o[rg][f][r] * inv);
        }
    }
}

// ---------------------------------------------------------------------------
extern "C" void kernel_launch(void* const* d_in, const int* in_sizes, int n_in,
                              void* d_out, int out_size, void* d_ws, size_t ws_size,
                              hipStream_t stream)
{
    const float* x      = (const float*)d_in[0];
    const float* W_attn = (const float*)d_in[1];
    const float* b_attn = (const float*)d_in[2];
    const float* W_proj = (const float*)d_in[3];
    const float* b_proj = (const float*)d_in[4];
    float* out = (float*)d_out;

    char* w = (char*)d_ws;
    u16* Qb = (u16*)w;  w += (size_t)BB * HH * TT * DD * 2;   // 8.39 MB
    u16* Kb = (u16*)w;  w += (size_t)BB * HH * TT * DD * 2;
    u16* Vb = (u16*)w;  w += (size_t)BB * HH * TT * DD * 2;
    u16* Xb = (u16*)w;  w += (size_t)BB * TT * CC * 2;        // 16.78 MB (aliases Yb)
    u16* WaT = (u16*)w; w += (size_t)CC * 3 * CC * 2;
    u16* WpT = (u16*)w; w += (size_t)CC * CC * 2;
    u16* Yb = Xb;

    const dim3 blk(256);

    cast_bf16<<<2048, blk, 0, stream>>>(x, Xb, BB * TT * CC / 4);
    transpose_cast<<<dim3(3 * CC / 32, CC / 32), blk, 0, stream>>>(W_attn, WaT, CC, 3 * CC);
    transpose_cast<<<dim3(CC / 32, CC / 32), blk, 0, stream>>>(W_proj, WpT, CC, CC);

    gemm_bf16<1><<<dim3(3 * CC / 128, BB * TT / 128), blk, 0, stream>>>(
        Xb, WaT, b_attn, nullptr, Qb, Kb, Vb, BB * TT, 3 * CC, CC);

    mfma_attn<<<dim3(2048), dim3(128), 0, stream>>>(Qb, Kb, Vb, Yb);

    gemm_bf16<0><<<dim3(CC / 128, BB * TT / 128), blk, 0, stream>>>(
        Yb, WpT, b_proj, out, nullptr, nullptr, nullptr, BB * TT, CC, CC);
}